// Round 8
// baseline (128.496 us; speedup 1.0000x reference)
//
#include <hip/hip_runtime.h>
#include <hip/hip_bf16.h>
#include <math.h>

#define DIMX 1024
#define HEADSX 16
#define HDX 64
#define BBX 2
#define SSX 2048
#define MMX (BBX*SSX)   // 4096 rows

typedef __bf16 bf16x8 __attribute__((ext_vector_type(8)));
typedef __bf16 bf16x4 __attribute__((ext_vector_type(4)));
typedef float  f32x4  __attribute__((ext_vector_type(4)));

#define NEGF (-1e30f)
#define QSCALE 0.18033688011112042f   // (1/sqrt(64)) * log2(e), folded into Q

// async 16B global->LDS. LDS dest must be wave-uniform base; HW adds lane*16.
static __device__ __forceinline__ void gload16(const void* g, void* l) {
  __builtin_amdgcn_global_load_lds(
      (const __attribute__((address_space(1))) unsigned int*)g,
      (__attribute__((address_space(3))) unsigned int*)l, 16, 0, 0);
}

// ------- kernel 1: fused prep: x fp32->bf16  +  W transpose->bf16 -------
__global__ __launch_bounds__(256) void k_prep(
    const float* __restrict__ x, const float* __restrict__ Wq,
    const float* __restrict__ Wk, const float* __restrict__ Wv,
    const float* __restrict__ Wo, __bf16* __restrict__ xb,
    __bf16* __restrict__ wqkvT, __bf16* __restrict__ woT) {
  const int bid = blockIdx.x;
  if (bid < 4096) {
    int i = (bid * 256 + threadIdx.x) * 4;
    float4 v = *(const float4*)&x[i];
    bf16x4 o = { (__bf16)v.x, (__bf16)v.y, (__bf16)v.z, (__bf16)v.w };
    *(bf16x4*)&xb[i] = o;
    return;
  }
  __shared__ __bf16 tile[64][65];
  const int wb = bid - 4096;
  const int mat = wb >> 8, t8 = wb & 255;
  const float* src = (mat == 0) ? Wq : (mat == 1) ? Wk : (mat == 2) ? Wv : Wo;
  __bf16* dst = (mat < 3) ? (wqkvT + (size_t)mat * DIMX * DIMX) : woT;
  const int tx = t8 & 15, ty = t8 >> 4;
  const int k0 = ty * 64, n0 = tx * 64;
  #pragma unroll
  for (int rep = 0; rep < 16; ++rep) {
    int idx = rep * 256 + threadIdx.x;
    int r = idx >> 6, c = idx & 63;
    tile[r][c] = (__bf16)src[(size_t)(k0 + r) * DIMX + n0 + c];
  }
  __syncthreads();
  #pragma unroll
  for (int rep = 0; rep < 16; ++rep) {
    int idx = rep * 256 + threadIdx.x;
    int r = idx >> 6, c = idx & 63;           // r = local n, c = local k
    dst[(size_t)(n0 + r) * DIMX + k0 + c] = tile[c][r];
  }
}

// ------------- kernel 3: QKV GEMM, 128x128 tile, BK=64, swizzled -------------
// LDS layout: row-major [128][64] with col-chunk XOR-swizzle (rule 21:
// linear gload_lds dest + inverse-swizzled global source + swizzled read).
__global__ __launch_bounds__(256) void k_gemm_qkv(
    const __bf16* __restrict__ A,    // [4096][1024]
    const __bf16* __restrict__ Bt,   // [3072][1024]
    const float* __restrict__ b0, const float* __restrict__ b1,
    const float* __restrict__ b2,
    __bf16* __restrict__ qb, __bf16* __restrict__ kb, __bf16* __restrict__ vtb) {
  constexpr int BK = 64, K = 1024;
  __shared__ __bf16 As[128 * BK];    // 16 KB
  __shared__ __bf16 Bs[128 * BK];    // 16 KB
  const int tid = threadIdx.x, lane = tid & 63, wave = tid >> 6;
  const int g = lane >> 4, r16 = lane & 15;
  const int wm = wave & 1, wn = wave >> 1;
  const int id = blockIdx.x;                 // 768 blocks = 8 XCD x 96
  const int xcd = id & 7, j96 = id >> 3;
  const int m0 = (xcd * 4 + (j96 & 3)) * 128;   // 32 m-tiles
  const int n0 = (j96 >> 2) * 128;              // 24 n-tiles

  f32x4 acc[4][4] = {};

  for (int k0 = 0; k0 < K; k0 += BK) {       // 16 iterations
    __syncthreads();
    #pragma unroll
    for (int i = 0; i < 4; ++i) {            // 1024 chunks per matrix
      int c = tid + 256 * i;
      int r = c >> 3, cb = (c & 7) ^ (r & 7);
      gload16(&A [(size_t)(m0 + r) * K + k0 + cb * 8],
              (char*)As + (size_t)(wave * 64 + 256 * i) * 16);
      gload16(&Bt[(size_t)(n0 + r) * K + k0 + cb * 8],
              (char*)Bs + (size_t)(wave * 64 + 256 * i) * 16);
    }
    __syncthreads();
    #pragma unroll
    for (int kk = 0; kk < 2; ++kk) {
      bf16x8 af[4], bfr[4];
      #pragma unroll
      for (int i = 0; i < 4; ++i) {
        int rr = wm * 64 + i * 16 + r16;
        af[i] = *(const bf16x8*)&As[rr * 64 + (((kk << 2) + g) ^ (rr & 7)) * 8];
      }
      #pragma unroll
      for (int j = 0; j < 4; ++j) {
        int rn = wn * 64 + j * 16 + r16;
        bfr[j] = *(const bf16x8*)&Bs[rn * 64 + (((kk << 2) + g) ^ (rn & 7)) * 8];
      }
      #pragma unroll
      for (int i = 0; i < 4; ++i)
        #pragma unroll
        for (int j = 0; j < 4; ++j)
          acc[i][j] = __builtin_amdgcn_mfma_f32_16x16x32_bf16(af[i], bfr[j],
                                                              acc[i][j], 0, 0, 0);
    }
  }

  #pragma unroll
  for (int i = 0; i < 4; ++i) {
    #pragma unroll
    for (int j = 0; j < 4; ++j) {
      #pragma unroll
      for (int r = 0; r < 4; ++r) {
        int m = m0 + wm * 64 + i * 16 + 4 * g + r;   // C row = (lane>>4)*4+reg
        int n = n0 + wn * 64 + j * 16 + r16;         // C col = lane&15
        float v = acc[i][j][r];
        int proj = n >> 10, w = n & 1023, h = w >> 6, d = w & 63;
        const float* bp = (proj == 0) ? b0 : (proj == 1) ? b1 : b2;
        v += bp[w];
        int b = m >> 11, s = m & 2047, bh = b * HEADSX + h;
        if (proj == 0)      qb [((size_t)bh * SSX + s) * HDX + d] =
                                (__bf16)(v * QSCALE);
        else if (proj == 1) kb [((size_t)bh * SSX + s) * HDX + d] = (__bf16)v;
        else                vtb[((size_t)bh * HDX + d) * SSX + s] = (__bf16)v;
      }
    }
  }
}

// ---------------- kernel 5: output GEMM, 128x64 tile, BK=64, swizzled ----------------
__global__ __launch_bounds__(256) void k_gemm_out(
    const __bf16* __restrict__ A,    // ctx [4096][1024]
    const __bf16* __restrict__ Bt,   // WoT [1024][1024]
    const float* __restrict__ bias, float* __restrict__ outf) {
  constexpr int BK = 64, K = 1024;
  __shared__ __bf16 As[128 * BK];    // 16 KB
  __shared__ __bf16 Bs[64 * BK];     // 8 KB
  const int tid = threadIdx.x, lane = tid & 63, wave = tid >> 6;
  const int g = lane >> 4, r16 = lane & 15;
  const int wm = wave & 1, wn = wave >> 1;
  const int id = blockIdx.x;                 // 512 blocks = 8 XCD x 64
  const int xcd = id & 7, j64 = id >> 3;
  const int m0 = (xcd * 4 + (j64 & 3)) * 128;   // 32 m-tiles
  const int n0 = (j64 >> 2) * 64;               // 16 n-tiles

  f32x4 acc[4][2] = {};

  for (int k0 = 0; k0 < K; k0 += BK) {
    __syncthreads();
    #pragma unroll
    for (int i = 0; i < 4; ++i) {            // A: 1024 chunks
      int c = tid + 256 * i;
      int r = c >> 3, cb = (c & 7) ^ (r & 7);
      gload16(&A[(size_t)(m0 + r) * K + k0 + cb * 8],
              (char*)As + (size_t)(wave * 64 + 256 * i) * 16);
    }
    #pragma unroll
    for (int i = 0; i < 2; ++i) {            // B: 512 chunks
      int c = tid + 256 * i;
      int r = c >> 3, cb = (c & 7) ^ (r & 7);
      gload16(&Bt[(size_t)(n0 + r) * K + k0 + cb * 8],
              (char*)Bs + (size_t)(wave * 64 + 256 * i) * 16);
    }
    __syncthreads();
    #pragma unroll
    for (int kk = 0; kk < 2; ++kk) {
      bf16x8 af[4], bfr[2];
      #pragma unroll
      for (int i = 0; i < 4; ++i) {
        int rr = wm * 64 + i * 16 + r16;
        af[i] = *(const bf16x8*)&As[rr * 64 + (((kk << 2) + g) ^ (rr & 7)) * 8];
      }
      #pragma unroll
      for (int j = 0; j < 2; ++j) {
        int rn = wn * 32 + j * 16 + r16;
        bfr[j] = *(const bf16x8*)&Bs[rn * 64 + (((kk << 2) + g) ^ (rn & 7)) * 8];
      }
      #pragma unroll
      for (int i = 0; i < 4; ++i)
        #pragma unroll
        for (int j = 0; j < 2; ++j)
          acc[i][j] = __builtin_amdgcn_mfma_f32_16x16x32_bf16(af[i], bfr[j],
                                                              acc[i][j], 0, 0, 0);
    }
  }

  #pragma unroll
  for (int i = 0; i < 4; ++i)
    #pragma unroll
    for (int j = 0; j < 2; ++j)
      #pragma unroll
      for (int r = 0; r < 4; ++r) {
        int m = m0 + wm * 64 + i * 16 + 4 * g + r;
        int n = n0 + wn * 32 + j * 16 + r16;
        outf[(size_t)m * DIMX + n] = acc[i][j][r] + bias[n];
      }
}

// -------- kernel 4: causal flash attention, 8-wave paired blocks --------
// 512 threads. Waves 0-3 own qH=31-p (16 rows each), waves 4-7 own qL=p.
// K/V staged once per kv-tile by ALL 8 waves, double-buffered. L-waves idle
// (barrier-only) on tiles t>=ntL. 512 blocks x 2/CU = 16 waves/CU (4/SIMD)
// vs 2/SIMD before: the round-5..7 plateau was wave-concurrency-bound.
__global__ __launch_bounds__(512, 4) void k_attn(
    const __bf16* __restrict__ qb, const __bf16* __restrict__ kb,
    const __bf16* __restrict__ vtb, __bf16* __restrict__ ctxb) {
  const int tid = threadIdx.x;
  const int lane = tid & 63, wq = tid >> 6;      // 8 waves
  const int g = lane >> 4, r16 = lane & 15;

  // XCD-chunked mapping: id%8 = XCD; 4 consecutive bh per XCD.
  const int id = blockIdx.x;
  const int xcd = id & 7, idx = id >> 3;
  const int bh = xcd * 4 + (idx & 3);
  const int p  = idx >> 2;                 // pair index 0..15
  const int b = bh >> 4, h = bh & 15;

  const int ntL = p + 1, ntH = 32 - p;     // ntL <= 16 < ntH always
  const bool isH = (wq < 4);
  const int myNt = isH ? ntH : ntL;
  const int q0 = isH ? ((31 - p) * 64 + wq * 16)
                     : (p * 64 + (wq - 4) * 16);

  const __bf16* Q  = qb  + (size_t)bh * SSX * HDX;
  const __bf16* Kp = kb  + (size_t)bh * SSX * HDX;
  const __bf16* Vt = vtb + (size_t)bh * HDX * SSX;

  __shared__ __bf16 Ks[2][64 * 64];    // 16 KB
  __shared__ __bf16 Vs[2][64 * 64];    // 16 KB
  __shared__ unsigned Pld[8][512];     // per-wave P^T scratch, 16 KB

  bf16x8 qf[2];
  qf[0] = *(const bf16x8*)&Q[(size_t)(q0 + r16) * HDX + g * 8];
  qf[1] = *(const bf16x8*)&Q[(size_t)(q0 + r16) * HDX + 32 + g * 8];

  f32x4 acc[4] = {};                // ctx^T: acc[j2][r]=ctx[d=j2*16+4g+r][q=r16]
  float mrun = NEGF, lrun = 0.f;
  const int qrow = q0 + r16;

  // stage tile t: 512 K-chunks + 512 V-chunks, 1+1 per thread.
  // LDS chunk (r, j) holds global (r, j^(r&7)); read undoes it.
  auto STAGE = [&](int buf, int t) {
    const int kv0 = t * 64;
    int c = tid;
    int r = c >> 3;
    int cb = (c & 7) ^ (r & 7);
    gload16(&Kp[(size_t)(kv0 + r) * HDX + cb * 8],
            (char*)Ks[buf] + (size_t)(wq * 64) * 16);
    gload16(&Vt[(size_t)r * SSX + kv0 + cb * 8],
            (char*)Vs[buf] + (size_t)(wq * 64) * 16);
  };

  STAGE(0, 0);
  __syncthreads();

  for (int t = 0; t < ntH; ++t) {
    const int cur = t & 1;
    if (t + 1 < ntH) STAGE(cur ^ 1, t + 1);   // async prefetch next tile
    if (t < myNt) {
      const int kv0 = t * 64;
      const bool last = (t == myNt - 1);

      // ---- S^T = K Q^T: sac[jj][r] = S[k=kv0+16jj+4g+r][q=r16] ----
      f32x4 sac[4] = {};
      __builtin_amdgcn_s_setprio(1);
      #pragma unroll
      for (int kk = 0; kk < 2; ++kk)
        #pragma unroll
        for (int jj = 0; jj < 4; ++jj) {
          int rr = jj * 16 + r16;
          bf16x8 kf = *(const bf16x8*)
              &Ks[cur][rr * 64 + (((kk << 2) + g) ^ (rr & 7)) * 8];
          sac[jj] = __builtin_amdgcn_mfma_f32_16x16x32_bf16(kf, qf[kk],
                                                            sac[jj], 0, 0, 0);
        }
      __builtin_amdgcn_s_setprio(0);

      // ---- causal mask (diagonal tile only), per-lane max ----
      float pv[4][4];
      float mt = NEGF;
      #pragma unroll
      for (int jj = 0; jj < 4; ++jj)
        #pragma unroll
        for (int r = 0; r < 4; ++r) {
          float s = sac[jj][r];
          if (last) {
            int kcol = kv0 + jj * 16 + 4 * g + r;
            s = (kcol > qrow) ? NEGF : s;
          }
          pv[jj][r] = s;
          mt = fmaxf(mt, s);
        }
      mt = fmaxf(mt, __shfl_xor(mt, 16));
      mt = fmaxf(mt, __shfl_xor(mt, 32));

      if (__any(mt > mrun)) {        // T13 defer-max (exact: P<=1 when skipped)
        float mnew = fmaxf(mrun, mt);
        float fac = exp2f(mrun - mnew);
        mrun = mnew;
        lrun *= fac;
        #pragma unroll
        for (int j2 = 0; j2 < 4; ++j2)
          #pragma unroll
          for (int r = 0; r < 4; ++r)
            acc[j2][r] *= fac;
      }
      float rs = 0.f;
      #pragma unroll
      for (int jj = 0; jj < 4; ++jj)
        #pragma unroll
        for (int r = 0; r < 4; ++r) {
          float px = exp2f(pv[jj][r] - mrun);
          pv[jj][r] = px;
          rs += px;
        }
      lrun += rs;                    // lane-partial; cross-g reduced at end

      // ---- pack P^T to bf16, store transposed (quad-swizzled dwords) ----
      #pragma unroll
      for (int jj = 0; jj < 4; ++jj)
        #pragma unroll
        for (int rp = 0; rp < 2; ++rp) {
          unsigned w;
          asm("v_cvt_pk_bf16_f32 %0, %1, %2"
              : "=v"(w) : "v"(pv[jj][2 * rp]), "v"(pv[jj][2 * rp + 1]));
          int c = jj * 8 + g * 2 + rp;                       // k/2
          int addr = r16 * 32 + (((c >> 2) ^ (r16 & 7)) << 2) + (c & 3);
          Pld[wq][addr] = w;
        }

      // ---- ctx^T += V^T P ----
      bf16x8 pf[2];
      #pragma unroll
      for (int half = 0; half < 2; ++half) {
        int c = half * 16 + g * 4;
        int addr = r16 * 32 + (((c >> 2) ^ (r16 & 7)) << 2);
        pf[half] = *(const bf16x8*)&Pld[wq][addr];
      }
      __builtin_amdgcn_s_setprio(1);
      #pragma unroll
      for (int j2 = 0; j2 < 4; ++j2)
        #pragma unroll
        for (int half = 0; half < 2; ++half) {
          int dd = j2 * 16 + r16;
          bf16x8 vf = *(const bf16x8*)
              &Vs[cur][dd * 64 + (((half << 2) + g) ^ (dd & 7)) * 8];
          acc[j2] = __builtin_amdgcn_mfma_f32_16x16x32_bf16(vf, pf[half],
                                                            acc[j2], 0, 0, 0);
        }
      __builtin_amdgcn_s_setprio(0);
    }
    __syncthreads();   // drains prefetch (vmcnt) + all LDS reads (lgkm)
  }

  // total row-sum: combine the 4 g-group partials
  lrun += __shfl_xor(lrun, 16);
  lrun += __shfl_xor(lrun, 32);
  const float inv = 1.f / lrun;
  const int s = q0 + r16;
  #pragma unroll
  for (int j2 = 0; j2 < 4; ++j2)
    #pragma unroll
    for (int r = 0; r < 4; ++r) {
      int d = j2 * 16 + 4 * g + r;
      ctxb[((size_t)(b * SSX + s)) * DIMX + h * HDX + d] =
          (__bf16)(acc[j2][r] * inv);
    }
}

extern "C" void kernel_launch(void* const* d_in, const int* in_sizes, int n_in,
                              void* d_out, int out_size, void* d_ws,
                              size_t ws_size, hipStream_t stream) {
  const float* x  = (const float*)d_in[0];
  const float* Wq = (const float*)d_in[1];
  const float* bq = (const float*)d_in[2];
  const float* Wk = (const float*)d_in[3];
  const float* bk = (const float*)d_in[4];
  const float* Wv = (const float*)d_in[5];
  const float* bv = (const float*)d_in[6];
  const float* Wo = (const float*)d_in[7];
  const float* bo = (const float*)d_in[8];
  float* out = (float*)d_out;

  char* ws = (char*)d_ws;                       // needs 40 MB
  __bf16* xb    = (__bf16*)(ws);                // 8 MB, reused as ctxb later
  __bf16* wqkvT = (__bf16*)(ws + ((size_t)8  << 20));  // 6 MB
  __bf16* woT   = (__bf16*)(ws + ((size_t)14 << 20));  // 2 MB
  __bf16* qb    = (__bf16*)(ws + ((size_t)16 << 20));  // 8 MB
  __bf16* kb    = (__bf16*)(ws + ((size_t)24 << 20));  // 8 MB
  __bf16* vtb   = (__bf16*)(ws + ((size_t)32 << 20));  // 8 MB (V^T)
  __bf16* ctxb  = xb;   // x dead after QKV GEMM

  k_prep<<<5120, 256, 0, stream>>>(x, Wq, Wk, Wv, Wo, xb, wqkvT, woT);
  k_gemm_qkv<<<768, 256, 0, stream>>>(xb, wqkvT, bq, bk, bv, qb, kb, vtb);
  k_attn<<<512, 512, 0, stream>>>(qb, kb, vtb, ctxb);
  k_gemm_out<<<512, 256, 0, stream>>>(ctxb, woT, bo, out);
}

// Round 9
// 120.703 us; speedup vs baseline: 1.0646x; 1.0646x over previous
//
#include <hip/hip_runtime.h>
#include <hip/hip_bf16.h>
#include <math.h>

#define DIMX 1024
#define HEADSX 16
#define HDX 64
#define BBX 2
#define SSX 2048
#define MMX (BBX*SSX)   // 4096 rows

typedef __bf16 bf16x8 __attribute__((ext_vector_type(8)));
typedef __bf16 bf16x4 __attribute__((ext_vector_type(4)));
typedef float  f32x4  __attribute__((ext_vector_type(4)));

#define NEGF (-1e30f)
#define QSCALE 0.18033688011112042f   // (1/sqrt(64)) * log2(e), folded into Q

// async 16B global->LDS. LDS dest must be wave-uniform base; HW adds lane*16.
static __device__ __forceinline__ void gload16(const void* g, void* l) {
  __builtin_amdgcn_global_load_lds(
      (const __attribute__((address_space(1))) unsigned int*)g,
      (__attribute__((address_space(3))) unsigned int*)l, 16, 0, 0);
}

// ------- kernel 1: fused prep: x fp32->bf16  +  W transpose->bf16 -------
__global__ __launch_bounds__(256) void k_prep(
    const float* __restrict__ x, const float* __restrict__ Wq,
    const float* __restrict__ Wk, const float* __restrict__ Wv,
    const float* __restrict__ Wo, __bf16* __restrict__ xb,
    __bf16* __restrict__ wqkvT, __bf16* __restrict__ woT) {
  const int bid = blockIdx.x;
  if (bid < 4096) {
    int i = (bid * 256 + threadIdx.x) * 4;
    float4 v = *(const float4*)&x[i];
    bf16x4 o = { (__bf16)v.x, (__bf16)v.y, (__bf16)v.z, (__bf16)v.w };
    *(bf16x4*)&xb[i] = o;
    return;
  }
  __shared__ __bf16 tile[64][65];
  const int wb = bid - 4096;
  const int mat = wb >> 8, t8 = wb & 255;
  const float* src = (mat == 0) ? Wq : (mat == 1) ? Wk : (mat == 2) ? Wv : Wo;
  __bf16* dst = (mat < 3) ? (wqkvT + (size_t)mat * DIMX * DIMX) : woT;
  const int tx = t8 & 15, ty = t8 >> 4;
  const int k0 = ty * 64, n0 = tx * 64;
  #pragma unroll
  for (int rep = 0; rep < 16; ++rep) {
    int idx = rep * 256 + threadIdx.x;
    int r = idx >> 6, c = idx & 63;
    tile[r][c] = (__bf16)src[(size_t)(k0 + r) * DIMX + n0 + c];
  }
  __syncthreads();
  #pragma unroll
  for (int rep = 0; rep < 16; ++rep) {
    int idx = rep * 256 + threadIdx.x;
    int r = idx >> 6, c = idx & 63;           // r = local n, c = local k
    dst[(size_t)(n0 + r) * DIMX + k0 + c] = tile[c][r];
  }
}

// ---------------- kernel 3: QKV GEMM, 128x128 tile, BK=32 (r7 form) ----------------
__global__ __launch_bounds__(256) void k_gemm_qkv(
    const __bf16* __restrict__ A,    // [4096][1024]
    const __bf16* __restrict__ Bt,   // [3072][1024]
    const float* __restrict__ b0, const float* __restrict__ b1,
    const float* __restrict__ b2,
    __bf16* __restrict__ qb, __bf16* __restrict__ kb, __bf16* __restrict__ vtb) {
  constexpr int BK = 32, K = 1024;
  __shared__ __bf16 As[128 * BK];
  __shared__ __bf16 Bs[128 * BK];
  const int tid = threadIdx.x, lane = tid & 63, wave = tid >> 6;
  const int g = lane >> 4, r16 = lane & 15;
  const int wm = wave & 1, wn = wave >> 1;
  const int id = blockIdx.x;                 // 768 blocks = 8 XCD x 96
  const int xcd = id & 7, j96 = id >> 3;
  const int m0 = (xcd * 4 + (j96 & 3)) * 128;   // 32 m-tiles
  const int n0 = (j96 >> 2) * 128;              // 24 n-tiles

  f32x4 acc[4][4] = {};

  for (int k0 = 0; k0 < K; k0 += BK) {
    __syncthreads();
    #pragma unroll
    for (int i = 0; i < 2; ++i) {
      int c = wave * 64 + lane + 256 * i;       // chunk id (512 x 16B per tile)
      gload16(&A [(size_t)(m0 + (c >> 2)) * K + k0 + (c & 3) * 8],
              (char*)As + (size_t)(wave * 64 + 256 * i) * 16);
      gload16(&Bt[(size_t)(n0 + (c >> 2)) * K + k0 + (c & 3) * 8],
              (char*)Bs + (size_t)(wave * 64 + 256 * i) * 16);
    }
    __syncthreads();
    bf16x8 af[4], bfr[4];
    #pragma unroll
    for (int i = 0; i < 4; ++i)
      af[i]  = *(const bf16x8*)&As[(wm * 64 + i * 16 + r16) * BK + g * 8];
    #pragma unroll
    for (int j = 0; j < 4; ++j)
      bfr[j] = *(const bf16x8*)&Bs[(wn * 64 + j * 16 + r16) * BK + g * 8];
    #pragma unroll
    for (int i = 0; i < 4; ++i)
      #pragma unroll
      for (int j = 0; j < 4; ++j)
        acc[i][j] = __builtin_amdgcn_mfma_f32_16x16x32_bf16(af[i], bfr[j],
                                                            acc[i][j], 0, 0, 0);
  }

  #pragma unroll
  for (int i = 0; i < 4; ++i) {
    #pragma unroll
    for (int j = 0; j < 4; ++j) {
      #pragma unroll
      for (int r = 0; r < 4; ++r) {
        int m = m0 + wm * 64 + i * 16 + 4 * g + r;   // C row = (lane>>4)*4+reg
        int n = n0 + wn * 64 + j * 16 + r16;         // C col = lane&15
        float v = acc[i][j][r];
        int proj = n >> 10, w = n & 1023, h = w >> 6, d = w & 63;
        const float* bp = (proj == 0) ? b0 : (proj == 1) ? b1 : b2;
        v += bp[w];
        int b = m >> 11, s = m & 2047, bh = b * HEADSX + h;
        if (proj == 0)      qb [((size_t)bh * SSX + s) * HDX + d] =
                                (__bf16)(v * QSCALE);
        else if (proj == 1) kb [((size_t)bh * SSX + s) * HDX + d] = (__bf16)v;
        else                vtb[((size_t)bh * HDX + d) * SSX + s] = (__bf16)v;
      }
    }
  }
}

// ---------------- kernel 5: output GEMM, 128x64 tile, BK=32 (r7 form) ----------------
__global__ __launch_bounds__(256) void k_gemm_out(
    const __bf16* __restrict__ A,    // ctx [4096][1024]
    const __bf16* __restrict__ Bt,   // WoT [1024][1024]
    const float* __restrict__ bias, float* __restrict__ outf) {
  constexpr int BK = 32, K = 1024;
  __shared__ __bf16 As[128 * BK];    // 8 KB
  __shared__ __bf16 Bs[64 * BK];     // 4 KB
  const int tid = threadIdx.x, lane = tid & 63, wave = tid >> 6;
  const int g = lane >> 4, r16 = lane & 15;
  const int wm = wave & 1, wn = wave >> 1;
  const int id = blockIdx.x;                 // 512 blocks = 8 XCD x 64
  const int xcd = id & 7, j64 = id >> 3;
  const int m0 = (xcd * 4 + (j64 & 3)) * 128;   // 32 m-tiles
  const int n0 = (j64 >> 2) * 64;               // 16 n-tiles

  f32x4 acc[4][2] = {};

  for (int k0 = 0; k0 < K; k0 += BK) {
    __syncthreads();
    #pragma unroll
    for (int i = 0; i < 2; ++i) {
      int c = wave * 64 + lane + 256 * i;      // A: 512 chunks
      gload16(&A [(size_t)(m0 + (c >> 2)) * K + k0 + (c & 3) * 8],
              (char*)As + (size_t)(wave * 64 + 256 * i) * 16);
    }
    {
      int c = tid;                             // B: 256 chunks
      gload16(&Bt[(size_t)(n0 + (c >> 2)) * K + k0 + (c & 3) * 8],
              (char*)Bs + (size_t)(wave * 64) * 16);
    }
    __syncthreads();
    bf16x8 af[4], bfr[2];
    #pragma unroll
    for (int i = 0; i < 4; ++i)
      af[i]  = *(const bf16x8*)&As[(wm * 64 + i * 16 + r16) * BK + g * 8];
    #pragma unroll
    for (int j = 0; j < 2; ++j)
      bfr[j] = *(const bf16x8*)&Bs[(wn * 32 + j * 16 + r16) * BK + g * 8];
    #pragma unroll
    for (int i = 0; i < 4; ++i)
      #pragma unroll
      for (int j = 0; j < 2; ++j)
        acc[i][j] = __builtin_amdgcn_mfma_f32_16x16x32_bf16(af[i], bfr[j],
                                                            acc[i][j], 0, 0, 0);
  }

  #pragma unroll
  for (int i = 0; i < 4; ++i)
    #pragma unroll
    for (int j = 0; j < 2; ++j)
      #pragma unroll
      for (int r = 0; r < 4; ++r) {
        int m = m0 + wm * 64 + i * 16 + 4 * g + r;
        int n = n0 + wn * 32 + j * 16 + r16;
        outf[(size_t)m * DIMX + n] = acc[i][j][r] + bias[n];
      }
}

// ---- kernel 4: causal flash attention, paired q-tiles, 2 kv-tiles/barrier ----
// r6 SUBTILE body, but the kv loop processes TWO staged tiles per
// __syncthreads() (4-slot K/V ring, prefetch distance 2). Barriers/block
// 33 -> 17; tile t's softmax overlaps tile t+1's QK (independent MFMAs).
__global__ __launch_bounds__(256, 2) void k_attn(
    const __bf16* __restrict__ qb, const __bf16* __restrict__ kb,
    const __bf16* __restrict__ vtb, __bf16* __restrict__ ctxb) {
  const int tid = threadIdx.x;
  const int lane = tid & 63, wq = tid >> 6;
  const int g = lane >> 4, r16 = lane & 15;

  // XCD-chunked mapping: id%8 = XCD; 4 consecutive bh per XCD.
  const int id = blockIdx.x;
  const int xcd = id & 7, idx = id >> 3;
  const int bh = xcd * 4 + (idx & 3);
  const int p  = idx >> 2;                 // pair index 0..15
  const int b = bh >> 4, h = bh & 15;

  const int ntL = p + 1, ntH = 32 - p;     // ntL <= 16 < ntH always
  const int q0L = p * 64 + wq * 16;
  const int q0H = (31 - p) * 64 + wq * 16;

  const __bf16* Q  = qb  + (size_t)bh * SSX * HDX;
  const __bf16* Kp = kb  + (size_t)bh * SSX * HDX;
  const __bf16* Vt = vtb + (size_t)bh * HDX * SSX;

  __shared__ __bf16 Ks[4][64 * 64];    // 32 KB, 4-slot ring
  __shared__ __bf16 Vs[4][64 * 64];    // 32 KB
  __shared__ unsigned Pld[4][512];     // per-wave P^T scratch, 8 KB

  bf16x8 qfL[2], qfH[2];
  qfL[0] = *(const bf16x8*)&Q[(size_t)(q0L + r16) * HDX + g * 8];
  qfL[1] = *(const bf16x8*)&Q[(size_t)(q0L + r16) * HDX + 32 + g * 8];
  qfH[0] = *(const bf16x8*)&Q[(size_t)(q0H + r16) * HDX + g * 8];
  qfH[1] = *(const bf16x8*)&Q[(size_t)(q0H + r16) * HDX + 32 + g * 8];

  f32x4 accL[4] = {}, accH[4] = {};    // ctx^T: acc[j2][r]=ctx[d=j2*16+4g+r][q=r16]
  float mrunL = NEGF, lrunL = 0.f;
  float mrunH = NEGF, lrunH = 0.f;

  // stage tile t into ring slot t&3. LDS chunk (r,cb) <- global (r, cb^(r&7)).
  auto STAGE = [&](int t) {
    const int slot = t & 3;
    const int kv0 = t * 64;
    #pragma unroll
    for (int i = 0; i < 2; ++i) {
      int c = tid + 256 * i;
      int r = c >> 3;
      int cb = (c & 7) ^ (r & 7);
      gload16(&Kp[(size_t)(kv0 + r) * HDX + cb * 8],
              (char*)Ks[slot] + (size_t)(wq * 64 + 256 * i) * 16);
      gload16(&Vt[(size_t)r * SSX + kv0 + cb * 8],
              (char*)Vs[slot] + (size_t)(wq * 64 + 256 * i) * 16);
    }
  };

  // one 16q x 64k sub-tile step against ring slot
  auto SUBTILE = [&](const bf16x8* qf, f32x4* acc, float& mrun, float& lrun,
                     int qrow, bool last, int kv0, int slot) {
    // ---- S^T = K Q^T: sac[jj][r] = S[k=kv0+16jj+4g+r][q=r16] (pre-scaled) ----
    f32x4 sac[4] = {};
    __builtin_amdgcn_s_setprio(1);
    #pragma unroll
    for (int kk = 0; kk < 2; ++kk)
      #pragma unroll
      for (int jj = 0; jj < 4; ++jj) {
        int rr = jj * 16 + r16;
        bf16x8 kf = *(const bf16x8*)
            &Ks[slot][rr * 64 + (((kk << 2) + g) ^ (rr & 7)) * 8];
        sac[jj] = __builtin_amdgcn_mfma_f32_16x16x32_bf16(kf, qf[kk], sac[jj],
                                                          0, 0, 0);
      }
    __builtin_amdgcn_s_setprio(0);

    // ---- causal mask (diagonal tile only), per-lane max ----
    float pv[4][4];
    float mt = NEGF;
    #pragma unroll
    for (int jj = 0; jj < 4; ++jj)
      #pragma unroll
      for (int r = 0; r < 4; ++r) {
        float s = sac[jj][r];
        if (last) {
          int kcol = kv0 + jj * 16 + 4 * g + r;
          s = (kcol > qrow) ? NEGF : s;
        }
        pv[jj][r] = s;
        mt = fmaxf(mt, s);
      }
    mt = fmaxf(mt, __shfl_xor(mt, 16));
    mt = fmaxf(mt, __shfl_xor(mt, 32));

    if (__any(mt > mrun)) {          // T13 defer-max (exact: P<=1 when skipped)
      float mnew = fmaxf(mrun, mt);
      float fac = exp2f(mrun - mnew);
      mrun = mnew;
      lrun *= fac;
      #pragma unroll
      for (int j2 = 0; j2 < 4; ++j2)
        #pragma unroll
        for (int r = 0; r < 4; ++r)
          acc[j2][r] *= fac;
    }
    float rs = 0.f;
    #pragma unroll
    for (int jj = 0; jj < 4; ++jj)
      #pragma unroll
      for (int r = 0; r < 4; ++r) {
        float px = exp2f(pv[jj][r] - mrun);
        pv[jj][r] = px;
        rs += px;
      }
    lrun += rs;                      // lane-partial; cross-g reduced at end

    // ---- pack P^T to bf16, store transposed (quad-swizzled dwords) ----
    #pragma unroll
    for (int jj = 0; jj < 4; ++jj)
      #pragma unroll
      for (int rp = 0; rp < 2; ++rp) {
        unsigned w;
        asm("v_cvt_pk_bf16_f32 %0, %1, %2"
            : "=v"(w) : "v"(pv[jj][2 * rp]), "v"(pv[jj][2 * rp + 1]));
        int c = jj * 8 + g * 2 + rp;                       // k/2
        int addr = r16 * 32 + (((c >> 2) ^ (r16 & 7)) << 2) + (c & 3);
        Pld[wq][addr] = w;
      }

    // ---- ctx^T += V^T P ----
    bf16x8 pf[2];
    #pragma unroll
    for (int half = 0; half < 2; ++half) {
      int c = half * 16 + g * 4;
      int addr = r16 * 32 + (((c >> 2) ^ (r16 & 7)) << 2);
      pf[half] = *(const bf16x8*)&Pld[wq][addr];
    }
    __builtin_amdgcn_s_setprio(1);
    #pragma unroll
    for (int j2 = 0; j2 < 4; ++j2)
      #pragma unroll
      for (int half = 0; half < 2; ++half) {
        int dd = j2 * 16 + r16;
        bf16x8 vf = *(const bf16x8*)
            &Vs[slot][dd * 64 + (((half << 2) + g) ^ (dd & 7)) * 8];
        acc[j2] = __builtin_amdgcn_mfma_f32_16x16x32_bf16(vf, pf[half],
                                                          acc[j2], 0, 0, 0);
      }
    __builtin_amdgcn_s_setprio(0);
  };

  STAGE(0);
  if (ntH > 1) STAGE(1);
  __syncthreads();

  for (int t = 0; t < ntH; t += 2) {
    if (t + 2 < ntH) STAGE(t + 2);            // prefetch into the other pair
    if (t + 3 < ntH) STAGE(t + 3);

    SUBTILE(qfH, accH, mrunH, lrunH, q0H + r16, t == ntH - 1, t * 64, t & 3);
    if (t < ntL)
      SUBTILE(qfL, accL, mrunL, lrunL, q0L + r16, t == ntL - 1, t * 64, t & 3);

    if (t + 1 < ntH) {
      SUBTILE(qfH, accH, mrunH, lrunH, q0H + r16, t + 1 == ntH - 1,
              (t + 1) * 64, (t + 1) & 3);
      if (t + 1 < ntL)
        SUBTILE(qfL, accL, mrunL, lrunL, q0L + r16, t + 1 == ntL - 1,
                (t + 1) * 64, (t + 1) & 3);
    }
    __syncthreads();   // drains this iteration's prefetch + LDS reads
  }

  auto EPIL = [&](f32x4* acc, float lrun, int q0) {
    lrun += __shfl_xor(lrun, 16);
    lrun += __shfl_xor(lrun, 32);
    const float inv = 1.f / lrun;
    const int s = q0 + r16;
    #pragma unroll
    for (int j2 = 0; j2 < 4; ++j2)
      #pragma unroll
      for (int r = 0; r < 4; ++r) {
        int d = j2 * 16 + 4 * g + r;
        ctxb[((size_t)(b * SSX + s)) * DIMX + h * HDX + d] =
            (__bf16)(acc[j2][r] * inv);
      }
  };
  EPIL(accH, lrunH, q0H);
  EPIL(accL, lrunL, q0L);
}

extern "C" void kernel_launch(void* const* d_in, const int* in_sizes, int n_in,
                              void* d_out, int out_size, void* d_ws,
                              size_t ws_size, hipStream_t stream) {
  const float* x  = (const float*)d_in[0];
  const float* Wq = (const float*)d_in[1];
  const float* bq = (const float*)d_in[2];
  const float* Wk = (const float*)d_in[3];
  const float* bk = (const float*)d_in[4];
  const float* Wv = (const float*)d_in[5];
  const float* bv = (const float*)d_in[6];
  const float* Wo = (const float*)d_in[7];
  const float* bo = (const float*)d_in[8];
  float* out = (float*)d_out;

  char* ws = (char*)d_ws;                       // needs 40 MB
  __bf16* xb    = (__bf16*)(ws);                // 8 MB, reused as ctxb later
  __bf16* wqkvT = (__bf16*)(ws + ((size_t)8  << 20));  // 6 MB
  __bf16* woT   = (__bf16*)(ws + ((size_t)14 << 20));  // 2 MB
  __bf16* qb    = (__bf16*)(ws + ((size_t)16 << 20));  // 8 MB
  __bf16* kb    = (__bf16*)(ws + ((size_t)24 << 20));  // 8 MB
  __bf16* vtb   = (__bf16*)(ws + ((size_t)32 << 20));  // 8 MB (V^T)
  __bf16* ctxb  = xb;   // x dead after QKV GEMM

  k_prep<<<5120, 256, 0, stream>>>(x, Wq, Wk, Wv, Wo, xb, wqkvT, woT);
  k_gemm_qkv<<<768, 256, 0, stream>>>(xb, wqkvT, bq, bk, bv, qb, kb, vtb);
  k_attn<<<512, 256, 0, stream>>>(qb, kb, vtb, ctxb);
  k_gemm_out<<<512, 256, 0, stream>>>(ctxb, woT, bo, out);
}